// Round 4
// baseline (434.032 us; speedup 1.0000x reference)
//
#include <hip/hip_runtime.h>

// LengthRegulator: B=64, T=512, D=384, MAX_LEN=4096
// Kernel A (B blocks, 1 barrier): wave-shuffle cumsum -> scatter idx[b,p] into d_ws,
//   tail -1 fill, mel_len (as float) to out tail.
// Kernel B (B*128 blocks): gather/copy; 32 idx values staged in LDS (broadcast reads),
//   contiguous float4 stores. Swizzled b-fastest for XCD L2 locality.
// Budget: 403 MB out write + ~50 MB x read + 2 MB idx ~= 455 MB @ 6.3 TB/s ~= 72 us floor.

#define T_DIM 512
#define D_DIM 384
#define D4    (D_DIM / 4)   // 96 float4 per row
#define ROWS  32            // output rows per copy-block
#define BLOCK 512
#define ITER  ((ROWS * D4) / BLOCK)  // 6

typedef float vfloat4 __attribute__((ext_vector_type(4)));

__global__ __launch_bounds__(BLOCK) void lr_scan_idx_kernel(
    const int* __restrict__ duration,  // [B, T]
    int*       __restrict__ idx,       // [B, ML]  (d_ws)
    float*     __restrict__ mel_out,   // [B] at out tail
    int ML)
{
    __shared__ int s_wsum[T_DIM / 64];  // 8 wave sums
    const int b    = blockIdx.x;
    const int tid  = threadIdx.x;
    const int lane = tid & 63;
    const int wid  = tid >> 6;

    const int d = duration[b * T_DIM + tid];

    // Inclusive wave scan via shuffles (no barriers).
    int v = d;
    #pragma unroll
    for (int off = 1; off < 64; off <<= 1) {
        int n = __shfl_up(v, off, 64);
        if (lane >= off) v += n;
    }
    if (lane == 63) s_wsum[wid] = v;
    __syncthreads();  // the only barrier

    int offset = 0, total = 0;
    #pragma unroll
    for (int w = 0; w < T_DIM / 64; ++w) {
        int s = s_wsum[w];
        if (w < wid) offset += s;
        total += s;
    }
    v += offset;                 // inclusive csum[tid]
    const int start = v - d;     // csum[tid-1]

    if (tid == 0) mel_out[b] = (float)total;

    int* __restrict__ idx_b = idx + b * ML;

    // Scatter: positions [csum[tid-1], csum[tid]) <- tid. Adjacent lanes write
    // adjacent ranges -> coalesced. p < total implies tid <= T-1 (no clip needed).
    for (int p = start; p < v; ++p) idx_b[p] = tid;

    // Tail: masked positions [total, ML) -> -1 (coalesced).
    for (int p = total + tid; p < ML; p += BLOCK) idx_b[p] = -1;
}

__global__ __launch_bounds__(BLOCK) void lr_copy_kernel(
    const float* __restrict__ x,    // [B, T, D]
    const int*   __restrict__ idx,  // [B, ML]
    float*       __restrict__ out,  // [B, ML, D]
    int B, int ML)
{
    __shared__ int s_idx[ROWS];

    // b fastest -> XCD (blockIdx % 8) == b % 8: batch pinned to one XCD's L2.
    const int b     = blockIdx.x % B;
    const int chunk = blockIdx.x / B;
    const int row0  = chunk * ROWS;
    const int tid   = threadIdx.x;

    if (tid < ROWS) s_idx[tid] = idx[b * ML + row0 + tid];
    __syncthreads();

    const vfloat4* __restrict__ x4   = (const vfloat4*)x;
    vfloat4*       __restrict__ out4 = (vfloat4*)out;

    const long long out_base = ((long long)b * ML + row0) * D4;
    const long long x_base   = (long long)b * T_DIM * D4;

    #pragma unroll
    for (int i = 0; i < ITER; ++i) {
        const int flat = tid + i * BLOCK;
        const int r = flat / D4;            // constant divisor -> magic mul
        const int j = flat - r * D4;
        const int t = s_idx[r];             // LDS broadcast (<=2 addrs per wave)
        vfloat4 v = (vfloat4)(0.f, 0.f, 0.f, 0.f);
        if (t >= 0) v = x4[x_base + (long long)t * D4 + j];
        out4[out_base + flat] = v;
    }
}

extern "C" void kernel_launch(void* const* d_in, const int* in_sizes, int n_in,
                              void* d_out, int out_size, void* d_ws, size_t ws_size,
                              hipStream_t stream) {
    const float* x   = (const float*)d_in[0];
    const int*   dur = (const int*)d_in[1];
    float*       out = (float*)d_out;
    int*         idx = (int*)d_ws;

    const int B  = in_sizes[1] / T_DIM;                 // 64
    const int ML = (out_size - B) / (B * D_DIM);        // 4096

    float* mel_out = out + (long long)B * ML * D_DIM;

    hipLaunchKernelGGL(lr_scan_idx_kernel, dim3(B), dim3(BLOCK), 0, stream,
                       dur, idx, mel_out, ML);

    const int grid = B * (ML / ROWS);                   // 8192 blocks
    hipLaunchKernelGGL(lr_copy_kernel, dim3(grid), dim3(BLOCK), 0, stream,
                       x, idx, out, B, ML);
}